// Round 1
// baseline (1432.066 us; speedup 1.0000x reference)
//
#include <hip/hip_runtime.h>

#define S_DIM 256
#define I_DIM 64
#define O_DIM 64
#define BATCH 64
#define TT 2048
#define CHUNK 64
#define NCHUNK (TT / CHUNK)  // 32

// ---------------- transpose: out[j*R + i] = in[i*C + j] ----------------
__global__ void k_transpose(const float* __restrict__ in, float* __restrict__ out,
                            int R, int C) {
  int idx = blockIdx.x * 256 + threadIdx.x;
  if (idx < R * C) {
    int i = idx / C, j = idx - i * C;
    out[j * R + i] = in[i * C + j];
  }
}

// ---------------- matsq: dst = src @ src (256x256 f32) ----------------
__global__ void k_matsq(const float* __restrict__ src, float* __restrict__ dst) {
  int i = blockIdx.x;
  int j = threadIdx.x;
  float acc = 0.f;
#pragma unroll 8
  for (int k = 0; k < 256; ++k)
    acc += src[i * 256 + k] * src[k * 256 + j];
  dst[i * 256 + j] = acc;
}

// ---------------- row-block GEMM with two concatenated inputs ----------------
// out[row, n] = sum_k1 A1[row,k1]*Wcat[k1,n] + sum_k2 A2[row,k2]*Wcat[K1+k2,n]
template <int N, int K1, int K2>
__global__ __launch_bounds__(256) void k_rowgemm(const float* __restrict__ A1,
                                                 const float* __restrict__ A2,
                                                 const float* __restrict__ Wcat,
                                                 float* __restrict__ out) {
  constexpr int KT = K1 + K2;      // 320 in both uses
  constexpr int TR = 32;           // rows per block
  constexpr int G = 256 / N;       // thread groups over rows
  constexpr int CNT = TR / G;      // rows per thread
  constexpr int PAD = 36;          // stride: 16B-aligned float4 reads, bank spread
  __shared__ float a_lds[KT * PAD];

  const int tid = threadIdx.x;
  const size_t row0 = (size_t)blockIdx.x * TR;

  // stage A rows (transposed) into LDS; global reads coalesced
  for (int idx = tid; idx < TR * KT; idx += 256) {
    int r = idx / KT, k = idx - r * KT;
    float v = (k < K1) ? A1[(row0 + r) * K1 + k]
                       : A2[(row0 + r) * K2 + (k - K1)];
    a_lds[k * PAD + r] = v;
  }
  __syncthreads();

  const int n = tid % N;
  const int g = tid / N;
  float acc[CNT];
#pragma unroll
  for (int j = 0; j < CNT; ++j) acc[j] = 0.f;

#pragma unroll 4
  for (int k = 0; k < KT; ++k) {
    float w = Wcat[k * N + n];  // coalesced, L1/L2 resident
#pragma unroll
    for (int j = 0; j < CNT; j += 4) {
      float4 av = *reinterpret_cast<const float4*>(&a_lds[k * PAD + g * CNT + j]);
      acc[j + 0] += av.x * w;
      acc[j + 1] += av.y * w;
      acc[j + 2] += av.z * w;
      acc[j + 3] += av.w * w;
    }
  }
#pragma unroll
  for (int j = 0; j < CNT; ++j)
    out[(row0 + g * CNT + j) * N + n] = acc[j];
}

// ---------------- chunked scan passes ----------------
// MODE 0: local scan, zero init, emit Lstate[c,b,:] only.
// MODE 1: true scan, init from E[c,b,:], write states into U in place.
template <int MODE>
__global__ __launch_bounds__(1024) void k_scan(const float* __restrict__ Ftr,
                                               float* __restrict__ U,
                                               const float* __restrict__ E,
                                               float* __restrict__ Lstate,
                                               int tasks_per_block) {
  extern __shared__ float lds[];
  float* u_lds = lds;                       // [CHUNK*256]
  float* s_lds = lds + CHUNK * 256;         // [256]
  float* p_lds = lds + CHUNK * 256 + 256;   // [4*256]

  const int tid = threadIdx.x;
  const int q = tid >> 8;    // 0..3 : K-quarter
  const int d = tid & 255;   // output element

  // per-thread F weights: w[j] = F[d][q*64+j]  (coalesced via Ftr)
  float w[64];
#pragma unroll
  for (int j = 0; j < 64; ++j) w[j] = Ftr[(q * 64 + j) * 256 + d];

  for (int it = 0; it < tasks_per_block; ++it) {
    int task = blockIdx.x * tasks_per_block + it;
    int b = task >> 5;            // NCHUNK = 32
    int c = task & (NCHUNK - 1);
    const int t0 = c * CHUNK;

    // prefetch this chunk's U into LDS (keeps global latency off serial path)
    const float4* usrc =
        reinterpret_cast<const float4*>(U + ((size_t)b * TT + t0) * 256);
    float4* u4 = reinterpret_cast<float4*>(u_lds);
    for (int idx = tid; idx < CHUNK * 256 / 4; idx += 1024) u4[idx] = usrc[idx];

    if (tid < 256)
      s_lds[tid] = (MODE == 0) ? 0.f : E[((size_t)c * BATCH + b) * 256 + tid];
    __syncthreads();

    for (int k = 0; k < CHUNK; ++k) {
      // phase A: partial matvec, s_lds reads are wave-uniform (broadcast)
      float acc = 0.f;
#pragma unroll
      for (int j = 0; j < 64; j += 4) {
        float4 sv = *reinterpret_cast<const float4*>(&s_lds[q * 64 + j]);
        acc += w[j] * sv.x + w[j + 1] * sv.y + w[j + 2] * sv.z + w[j + 3] * sv.w;
      }
      p_lds[q * 256 + d] = acc;
      __syncthreads();
      // phase B: reduce 4 partials, add u_t, advance state
      if (tid < 256) {
        float x = p_lds[tid] + p_lds[256 + tid] + p_lds[512 + tid] +
                  p_lds[768 + tid] + u_lds[k * 256 + tid];
        if (MODE == 1) U[((size_t)b * TT + t0 + k) * 256 + tid] = x;
        if (MODE == 0 && k == CHUNK - 1)
          Lstate[((size_t)c * BATCH + b) * 256 + tid] = x;
        s_lds[tid] = x;
      }
      __syncthreads();
    }
  }
}

// ---------------- chunk-carry: e_{c+1} = F^CHUNK * e_c + Lstate[c] ----------------
__global__ __launch_bounds__(1024) void k_carry(const float* __restrict__ FLtr,
                                                const float* __restrict__ state0,
                                                const float* __restrict__ Lstate,
                                                float* __restrict__ E) {
  __shared__ float s_lds[256];
  __shared__ float p_lds[4 * 256];
  const int tid = threadIdx.x;
  const int q = tid >> 8;
  const int d = tid & 255;
  const int b = blockIdx.x;

  float w[64];
#pragma unroll
  for (int j = 0; j < 64; ++j) w[j] = FLtr[(q * 64 + j) * 256 + d];

  if (tid < 256) {
    float e0 = state0[b * 256 + tid];
    s_lds[tid] = e0;
    E[(size_t)b * 256 + tid] = e0;  // E[0] = initial state
  }
  __syncthreads();

  for (int c = 0; c < NCHUNK - 1; ++c) {
    float lval = (tid < 256) ? Lstate[((size_t)c * BATCH + b) * 256 + tid] : 0.f;
    float acc = 0.f;
#pragma unroll
    for (int j = 0; j < 64; j += 4) {
      float4 sv = *reinterpret_cast<const float4*>(&s_lds[q * 64 + j]);
      acc += w[j] * sv.x + w[j + 1] * sv.y + w[j + 2] * sv.z + w[j + 3] * sv.w;
    }
    p_lds[q * 256 + d] = acc;
    __syncthreads();
    if (tid < 256) {
      float x = p_lds[tid] + p_lds[256 + tid] + p_lds[512 + tid] +
                p_lds[768 + tid] + lval;
      E[((size_t)(c + 1) * BATCH + b) * 256 + tid] = x;
      s_lds[tid] = x;
    }
    __syncthreads();
  }
}

extern "C" void kernel_launch(void* const* d_in, const int* in_sizes, int n_in,
                              void* d_out, int out_size, void* d_ws, size_t ws_size,
                              hipStream_t stream) {
  const float* state  = (const float*)d_in[0];
  const float* inputs = (const float*)d_in[1];
  const float* eps_W  = (const float*)d_in[2];
  const float* eps_V  = (const float*)d_in[3];
  const float* F      = (const float*)d_in[4];
  const float* B_mat  = (const float*)d_in[5];
  const float* H      = (const float*)d_in[6];
  const float* SW     = (const float*)d_in[7];
  const float* SV     = (const float*)d_in[8];

  float* out = (float*)d_out;
  float* states_out = out;                                  // [64][2048][256]
  float* obs_out = out + (size_t)BATCH * TT * S_DIM;        // [64][2048][64]

  // small scratch in ws (~1.2 MB)
  float* ws    = (float*)d_ws;
  float* Wcat1 = ws;                       // [320][256]
  float* Wcat2 = Wcat1 + 320 * 256;        // [320][64]
  float* Ftr   = Wcat2 + 320 * 64;         // [256][256] = F^T
  float* Pa    = Ftr + 256 * 256;          // power ping
  float* Pb    = Pa + 256 * 256;           // power pong
  // big scratch lives in the obs region of d_out (dead until final GEMM)
  float* Lst = obs_out;                                   // [32][64][256]
  float* E   = obs_out + (size_t)NCHUNK * BATCH * S_DIM;  // [32][64][256]

  // weight transposes (concatenated K layouts for coalesced access)
  k_transpose<<<(256 * 64 + 255) / 256, 256, 0, stream>>>(B_mat, Wcat1, 256, 64);
  k_transpose<<<(256 * 256 + 255) / 256, 256, 0, stream>>>(SW, Wcat1 + 64 * 256, 256, 256);
  k_transpose<<<(64 * 256 + 255) / 256, 256, 0, stream>>>(H, Wcat2, 64, 256);
  k_transpose<<<(64 * 64 + 255) / 256, 256, 0, stream>>>(SV, Wcat2 + 256 * 64, 64, 64);
  k_transpose<<<(256 * 256 + 255) / 256, 256, 0, stream>>>(F, Ftr, 256, 256);

  // (F^64)^T via 6 squarings of F^T:  (M^2)^T = (M^T)^2
  k_matsq<<<256, 256, 0, stream>>>(Ftr, Pa);  // F^2
  k_matsq<<<256, 256, 0, stream>>>(Pa, Pb);   // F^4
  k_matsq<<<256, 256, 0, stream>>>(Pb, Pa);   // F^8
  k_matsq<<<256, 256, 0, stream>>>(Pa, Pb);   // F^16
  k_matsq<<<256, 256, 0, stream>>>(Pb, Pa);   // F^32
  k_matsq<<<256, 256, 0, stream>>>(Pa, Pb);   // Pb = (F^64)^T

  // U = inputs@B^T + eps_W@SW^T  -> staged into states region of d_out
  k_rowgemm<256, 64, 256><<<BATCH * TT / 32, 256, 0, stream>>>(
      inputs, eps_W, Wcat1, states_out);

  const size_t lds_bytes = (CHUNK * 256 + 256 + 4 * 256) * sizeof(float);
  // pass 1: local scans -> Lstate
  k_scan<0><<<256, 1024, lds_bytes, stream>>>(Ftr, states_out, E, Lst,
                                              (BATCH * NCHUNK) / 256);
  // carry across chunks -> E
  k_carry<<<BATCH, 1024, 0, stream>>>(Pb, state, Lst, E);
  // pass 3: true scans, states written in place over U
  k_scan<1><<<256, 1024, lds_bytes, stream>>>(Ftr, states_out, E, Lst,
                                              (BATCH * NCHUNK) / 256);
  // observations = states@H^T + eps_V@SV^T
  k_rowgemm<64, 256, 64><<<BATCH * TT / 32, 256, 0, stream>>>(
      states_out, eps_V, Wcat2, obs_out);
}

// Round 3
// 1195.611 us; speedup vs baseline: 1.1978x; 1.1978x over previous
//
#include <hip/hip_runtime.h>

#define S_DIM 256
#define I_DIM 64
#define O_DIM 64
#define BATCH 64
#define TT 2048
#define CHUNK 64
#define NCHUNK (TT / CHUNK)  // 32
#define NTASK (BATCH * NCHUNK)  // 2048

typedef __attribute__((ext_vector_type(8))) short short8v;   // 8 bf16 = 4 VGPR
typedef __attribute__((ext_vector_type(4))) float float4v;   // MFMA acc

__device__ inline unsigned short f2bf(float f) {
  unsigned x = __float_as_uint(f);
  unsigned r = (x + 0x7FFFu + ((x >> 16) & 1u)) >> 16;  // RNE
  return (unsigned short)r;
}

// ---------------- transpose: out[j*R + i] = in[i*C + j] ----------------
__global__ void k_transpose(const float* __restrict__ in, float* __restrict__ out,
                            int R, int C) {
  int idx = blockIdx.x * 256 + threadIdx.x;
  if (idx < R * C) {
    int i = idx / C, j = idx - i * C;
    out[j * R + i] = in[i * C + j];
  }
}

// ------------- power-stack doubling: stack[m+j] = stack[j] @ stack[m-1] -------------
// stack[p] = F^(p+1), row-major [d][s]. Launch <<<m*256, 256>>>.
__global__ void k_powstage(float* __restrict__ stack, int m) {
  const int j = blockIdx.x >> 8;
  const int i = blockIdx.x & 255;
  const int d = threadIdx.x;
  const float* A = stack + (size_t)j * 65536 + i * 256;
  const float* Bm = stack + (size_t)(m - 1) * 65536;
  float acc = 0.f;
#pragma unroll 8
  for (int k = 0; k < 256; ++k) acc += A[k] * Bm[k * 256 + d];
  stack[(size_t)(m + j) * 65536 + i * 256 + d] = acc;
}

// ------------- f32 -> bf16 elementwise (float4 granularity) -------------
__global__ void k_bfcvt(const float* __restrict__ src, unsigned short* __restrict__ dst) {
  int i = blockIdx.x * 256 + threadIdx.x;  // one float4 each; grid covers exactly n/4
  float4 v = reinterpret_cast<const float4*>(src)[i];
  ushort4 o;
  o.x = f2bf(v.x); o.y = f2bf(v.y); o.z = f2bf(v.z); o.w = f2bf(v.w);
  reinterpret_cast<ushort4*>(dst)[i] = o;
}

// ---------------- row-block GEMM with two concatenated inputs (f32) ----------------
template <int N, int K1, int K2>
__global__ __launch_bounds__(256) void k_rowgemm(const float* __restrict__ A1,
                                                 const float* __restrict__ A2,
                                                 const float* __restrict__ Wcat,
                                                 float* __restrict__ out) {
  constexpr int KT = K1 + K2;
  constexpr int TR = 32;
  constexpr int G = 256 / N;
  constexpr int CNT = TR / G;
  constexpr int PAD = 36;
  __shared__ float a_lds[KT * PAD];

  const int tid = threadIdx.x;
  const size_t row0 = (size_t)blockIdx.x * TR;

  for (int idx = tid; idx < TR * KT; idx += 256) {
    int r = idx / KT, k = idx - r * KT;
    float v = (k < K1) ? A1[(row0 + r) * K1 + k]
                       : A2[(row0 + r) * K2 + (k - K1)];
    a_lds[k * PAD + r] = v;
  }
  __syncthreads();

  const int n = tid % N;
  const int g = tid / N;
  float acc[CNT];
#pragma unroll
  for (int j = 0; j < CNT; ++j) acc[j] = 0.f;

#pragma unroll 4
  for (int k = 0; k < KT; ++k) {
    float w = Wcat[k * N + n];
#pragma unroll
    for (int j = 0; j < CNT; j += 4) {
      float4 av = *reinterpret_cast<const float4*>(&a_lds[k * PAD + g * CNT + j]);
      acc[j + 0] += av.x * w;
      acc[j + 1] += av.y * w;
      acc[j + 2] += av.z * w;
      acc[j + 3] += av.w * w;
    }
  }
#pragma unroll
  for (int j = 0; j < CNT; ++j)
    out[(row0 + g * CNT + j) * N + n] = acc[j];
}

// ---------------- local chunk scan (zero init), writes y in place + Lstate ----------------
// 512 threads: g = tid>>6 (K-eighth), d4 = tid&63; thread owns outputs d4, d4+64, d4+128, d4+192.
__global__ __launch_bounds__(512, 2) void k_scan(const float* __restrict__ Ftr,
                                                 float* __restrict__ U,
                                                 float* __restrict__ Lst,
                                                 int tasks_per_block) {
  extern __shared__ float lds[];
  float* u_lds = lds;                      // [64*256]
  float* s_lds = lds + 64 * 256;           // [256]
  float* p_lds = lds + 64 * 256 + 256;     // [8*256]

  const int tid = threadIdx.x;
  const int g = tid >> 6;
  const int d4 = tid & 63;

  float w[4][32];  // 128 VGPRs, fully unrolled access (no spill)
#pragma unroll
  for (int j = 0; j < 32; ++j) {
#pragma unroll
    for (int o = 0; o < 4; ++o) w[o][j] = Ftr[(g * 32 + j) * 256 + o * 64 + d4];
  }

  for (int it = 0; it < tasks_per_block; ++it) {
    const int task = blockIdx.x * tasks_per_block + it;
    const int b = task >> 5;           // 32 chunks per batch
    const int c = task & (NCHUNK - 1);
    float* ubase = U + ((size_t)b * TT + c * CHUNK) * 256;

    const float4* us = reinterpret_cast<const float4*>(ubase);
    float4* u4 = reinterpret_cast<float4*>(u_lds);
#pragma unroll
    for (int i = 0; i < 8; ++i) u4[tid + i * 512] = us[tid + i * 512];
    if (tid < 256) s_lds[tid] = 0.f;
    __syncthreads();

    for (int k = 0; k < CHUNK; ++k) {
      float a0 = 0.f, a1 = 0.f, a2 = 0.f, a3 = 0.f;
#pragma unroll
      for (int j = 0; j < 32; j += 4) {
        float4 sv = *reinterpret_cast<const float4*>(&s_lds[g * 32 + j]);
        a0 += w[0][j] * sv.x + w[0][j + 1] * sv.y + w[0][j + 2] * sv.z + w[0][j + 3] * sv.w;
        a1 += w[1][j] * sv.x + w[1][j + 1] * sv.y + w[1][j + 2] * sv.z + w[1][j + 3] * sv.w;
        a2 += w[2][j] * sv.x + w[2][j + 1] * sv.y + w[2][j + 2] * sv.z + w[2][j + 3] * sv.w;
        a3 += w[3][j] * sv.x + w[3][j + 1] * sv.y + w[3][j + 2] * sv.z + w[3][j + 3] * sv.w;
      }
      p_lds[g * 256 + d4      ] = a0;
      p_lds[g * 256 + d4 + 64 ] = a1;
      p_lds[g * 256 + d4 + 128] = a2;
      p_lds[g * 256 + d4 + 192] = a3;
      __syncthreads();
      if (tid < 256) {
        float x = u_lds[k * 256 + tid];
#pragma unroll
        for (int gg = 0; gg < 8; ++gg) x += p_lds[gg * 256 + tid];
        ubase[k * 256 + tid] = x;  // y written in place over u
        if (k == CHUNK - 1) Lst[((size_t)c * BATCH + b) * 256 + tid] = x;
        s_lds[tid] = x;
      }
      __syncthreads();
    }
  }
}

// ---------------- chunk carry: e_{c+1} = F^64 e_c + Lst[c]; writes Ebf (bf16) ----------------
__global__ __launch_bounds__(512) void k_carry(const float* __restrict__ FLtr,
                                               const float* __restrict__ state0,
                                               const float* __restrict__ Lst,
                                               unsigned short* __restrict__ Ebf) {
  __shared__ float s_lds[256];
  __shared__ float p_lds[8 * 256];
  const int tid = threadIdx.x;
  const int g = tid >> 6;
  const int d4 = tid & 63;
  const int b = blockIdx.x;

  float w[4][32];
#pragma unroll
  for (int j = 0; j < 32; ++j) {
#pragma unroll
    for (int o = 0; o < 4; ++o) w[o][j] = FLtr[(g * 32 + j) * 256 + o * 64 + d4];
  }

  if (tid < 256) {
    float e0 = state0[b * 256 + tid];
    s_lds[tid] = e0;
    Ebf[(size_t)b * 256 + tid] = f2bf(e0);  // E[0] = initial state
  }
  __syncthreads();

  for (int c = 0; c < NCHUNK - 1; ++c) {
    float a0 = 0.f, a1 = 0.f, a2 = 0.f, a3 = 0.f;
#pragma unroll
    for (int j = 0; j < 32; j += 4) {
      float4 sv = *reinterpret_cast<const float4*>(&s_lds[g * 32 + j]);
      a0 += w[0][j] * sv.x + w[0][j + 1] * sv.y + w[0][j + 2] * sv.z + w[0][j + 3] * sv.w;
      a1 += w[1][j] * sv.x + w[1][j + 1] * sv.y + w[1][j + 2] * sv.z + w[1][j + 3] * sv.w;
      a2 += w[2][j] * sv.x + w[2][j + 1] * sv.y + w[2][j + 2] * sv.z + w[2][j + 3] * sv.w;
      a3 += w[3][j] * sv.x + w[3][j + 1] * sv.y + w[3][j + 2] * sv.z + w[3][j + 3] * sv.w;
    }
    p_lds[g * 256 + d4      ] = a0;
    p_lds[g * 256 + d4 + 64 ] = a1;
    p_lds[g * 256 + d4 + 128] = a2;
    p_lds[g * 256 + d4 + 192] = a3;
    __syncthreads();
    if (tid < 256) {
      float x = Lst[((size_t)c * BATCH + b) * 256 + tid];
#pragma unroll
      for (int gg = 0; gg < 8; ++gg) x += p_lds[gg * 256 + tid];
      Ebf[((size_t)(c + 1) * BATCH + b) * 256 + tid] = f2bf(x);
      s_lds[tid] = x;
    }
    __syncthreads();
  }
}

// ---------------- correction: states[task, j, :] += F^{j+1} @ e[task]  (bf16 MFMA) ----------------
// A = Ebf [2048 x 256] bf16, B^T = stackbf[j] [256d x 256s] bf16 (k-contiguous), C += into states.
// Block: 32 tasks x 256 d, fixed j. 4 waves: wave w -> M-half (w&1), N-half (w>>1) of 8 N-frags.
__global__ __launch_bounds__(256) void k_corr(const unsigned short* __restrict__ Ebf,
                                              const unsigned short* __restrict__ stackbf,
                                              float* __restrict__ states) {
  const int tb = blockIdx.x & 63;   // task block (32 tasks)
  const int jb = blockIdx.x >> 6;   // j in [0,64): correction F^{jb+1}
  const int tid = threadIdx.x;
  const int w = tid >> 6;
  const int l = tid & 63;
  const int lo = l & 15, hi = l >> 4;

  const int M0 = tb * 32 + (w & 1) * 16;   // M-half of 32-task tile
  const int nbase = (w >> 1) * 128;        // N-half of 256 outputs (8 frags each)
  const unsigned short* Bj = stackbf + (size_t)jb * 65536;

  float4v acc[8];
#pragma unroll
  for (int nf = 0; nf < 8; ++nf) acc[nf] = (float4v){0.f, 0.f, 0.f, 0.f};

#pragma unroll
  for (int kk = 0; kk < 8; ++kk) {
    const int k0 = kk * 32;
    short8v a = *reinterpret_cast<const short8v*>(Ebf + (size_t)(M0 + lo) * 256 + k0 + hi * 8);
#pragma unroll
    for (int nf = 0; nf < 8; ++nf) {
      const int d0 = nbase + nf * 16;
      short8v bv = *reinterpret_cast<const short8v*>(Bj + (size_t)(d0 + lo) * 256 + k0 + hi * 8);
      acc[nf] = __builtin_amdgcn_mfma_f32_16x16x32_bf16(a, bv, acc[nf], 0, 0, 0);
    }
  }

  // C/D layout (m89-verified): col = lane&15, row = (lane>>4)*4 + reg
#pragma unroll
  for (int nf = 0; nf < 8; ++nf) {
    const int d = nbase + nf * 16 + lo;
#pragma unroll
    for (int r = 0; r < 4; ++r) {
      const int task = M0 + hi * 4 + r;       // task = c*64 + b (matches Ebf layout)
      const int bb = task & 63, cc = task >> 6;
      size_t addr = (((size_t)bb * TT) + cc * CHUNK + jb) * 256 + d;
      states[addr] = states[addr] + acc[nf][r];
    }
  }
}

extern "C" void kernel_launch(void* const* d_in, const int* in_sizes, int n_in,
                              void* d_out, int out_size, void* d_ws, size_t ws_size,
                              hipStream_t stream) {
  const float* state  = (const float*)d_in[0];
  const float* inputs = (const float*)d_in[1];
  const float* eps_W  = (const float*)d_in[2];
  const float* eps_V  = (const float*)d_in[3];
  const float* F      = (const float*)d_in[4];
  const float* B_mat  = (const float*)d_in[5];
  const float* H      = (const float*)d_in[6];
  const float* SW     = (const float*)d_in[7];
  const float* SV     = (const float*)d_in[8];

  float* out = (float*)d_out;
  float* states_out = out;                                 // [64][2048][256]
  float* obs_out = out + (size_t)BATCH * TT * S_DIM;       // [64][2048][64] — scratch until last GEMM

  // small scratch in ws (~0.93 MB)
  float* ws    = (float*)d_ws;
  float* Wcat1 = ws;                        // [320][256]
  float* Wcat2 = Wcat1 + 320 * 256;         // [320][64]
  float* Ftr   = Wcat2 + 320 * 64;          // [256][256] = F^T
  float* FLtr  = Ftr + 256 * 256;           // [256][256] = (F^64)^T

  // big scratch in the dead obs region (28.2 MB of 33.5 MB)
  float* Lst              = obs_out;                          // [32][64][256] f32
  float* stack_F          = Lst + (size_t)NCHUNK * BATCH * 256;      // [64][256][256] f32, stack[p]=F^(p+1)
  unsigned short* stackbf = (unsigned short*)(stack_F + (size_t)64 * 65536);  // [64][256][256] bf16
  unsigned short* Ebf     = stackbf + (size_t)64 * 65536;     // [32][64][256] bf16

  // weight transposes
  k_transpose<<<64, 256, 0, stream>>>(B_mat, Wcat1, 256, 64);
  k_transpose<<<256, 256, 0, stream>>>(SW, Wcat1 + 64 * 256, 256, 256);
  k_transpose<<<64, 256, 0, stream>>>(H, Wcat2, 64, 256);
  k_transpose<<<16, 256, 0, stream>>>(SV, Wcat2 + 256 * 64, 64, 64);
  k_transpose<<<256, 256, 0, stream>>>(F, Ftr, 256, 256);

  // power stack F^1..F^64 by doubling (row-major, F-form)
  hipMemcpyAsync(stack_F, F, 65536 * sizeof(float), hipMemcpyDeviceToDevice, stream);
  k_powstage<<<1 * 256, 256, 0, stream>>>(stack_F, 1);
  k_powstage<<<2 * 256, 256, 0, stream>>>(stack_F, 2);
  k_powstage<<<4 * 256, 256, 0, stream>>>(stack_F, 4);
  k_powstage<<<8 * 256, 256, 0, stream>>>(stack_F, 8);
  k_powstage<<<16 * 256, 256, 0, stream>>>(stack_F, 16);
  k_powstage<<<32 * 256, 256, 0, stream>>>(stack_F, 32);
  k_transpose<<<256, 256, 0, stream>>>(stack_F + (size_t)63 * 65536, FLtr, 256, 256);
  k_bfcvt<<<64 * 65536 / 4 / 256, 256, 0, stream>>>(stack_F, stackbf);

  // U = inputs@B^T + eps_W@SW^T  (f32, feeds the feedback path)
  k_rowgemm<256, 64, 256><<<BATCH * TT / 32, 256, 0, stream>>>(
      inputs, eps_W, Wcat1, states_out);

  // pass 1: local scans (zero init), y in place + Lstate
  const size_t lds_bytes = (CHUNK * 256 + 256 + 8 * 256) * sizeof(float);
  k_scan<<<512, 512, lds_bytes, stream>>>(Ftr, states_out, Lst, NTASK / 512);

  // carry across chunks -> Ebf
  k_carry<<<BATCH, 512, 0, stream>>>(FLtr, state, Lst, Ebf);

  // correction: states = y + F^{j+1} e  (bf16 MFMA, no feedback -> bf16 safe)
  k_corr<<<64 * 64, 256, 0, stream>>>(Ebf, stackbf, states_out);

  // observations = states@H^T + eps_V@SV^T (overwrites scratch region)
  k_rowgemm<64, 256, 64><<<BATCH * TT / 32, 256, 0, stream>>>(
      states_out, eps_V, Wcat2, obs_out);
}

// Round 4
// 990.097 us; speedup vs baseline: 1.4464x; 1.2076x over previous
//
#include <hip/hip_runtime.h>

#define S_DIM 256
#define I_DIM 64
#define O_DIM 64
#define BATCH 64
#define TT 2048
#define CHUNK 64
#define NCHUNK (TT / CHUNK)  // 32
#define NTASK (BATCH * NCHUNK)  // 2048

typedef __attribute__((ext_vector_type(8))) short short8v;   // 8 bf16 = 4 VGPR
typedef __attribute__((ext_vector_type(4))) float float4v;   // MFMA acc

__device__ inline unsigned short f2bf(float f) {
  unsigned x = __float_as_uint(f);
  unsigned r = (x + 0x7FFFu + ((x >> 16) & 1u)) >> 16;  // RNE
  return (unsigned short)r;
}

// ---------------- transpose: out[j*R + i] = in[i*C + j] ----------------
__global__ void k_transpose(const float* __restrict__ in, float* __restrict__ out,
                            int R, int C) {
  int idx = blockIdx.x * 256 + threadIdx.x;
  if (idx < R * C) {
    int i = idx / C, j = idx - i * C;
    out[j * R + i] = in[i * C + j];
  }
}

// ------------- power-stack doubling: stack[m+j] = stack[j] @ stack[m-1] -------------
__global__ void k_powstage(float* __restrict__ stack, int m) {
  const int j = blockIdx.x >> 8;
  const int i = blockIdx.x & 255;
  const int d = threadIdx.x;
  const float* A = stack + (size_t)j * 65536 + i * 256;
  const float* Bm = stack + (size_t)(m - 1) * 65536;
  float acc = 0.f;
#pragma unroll 8
  for (int k = 0; k < 256; ++k) acc += A[k] * Bm[k * 256 + d];
  stack[(size_t)(m + j) * 65536 + i * 256 + d] = acc;
}

// ------------- f32 -> bf16 elementwise (float4 granularity) -------------
__global__ void k_bfcvt(const float* __restrict__ src, unsigned short* __restrict__ dst) {
  int i = blockIdx.x * 256 + threadIdx.x;
  float4 v = reinterpret_cast<const float4*>(src)[i];
  ushort4 o;
  o.x = f2bf(v.x); o.y = f2bf(v.y); o.z = f2bf(v.z); o.w = f2bf(v.w);
  reinterpret_cast<ushort4*>(dst)[i] = o;
}

// ------------- weight split: Wd[n][k] = concat(s1,s2) rows; hi/lo bf16 -------------
__global__ void k_wsplit(const float* __restrict__ s1, const float* __restrict__ s2,
                         int K1, int K2, unsigned short* __restrict__ hi,
                         unsigned short* __restrict__ lo, int total) {
  int idx = blockIdx.x * 256 + threadIdx.x;
  if (idx >= total) return;
  int KT = K1 + K2;
  int n = idx / KT, k = idx - n * KT;
  float a = (k < K1) ? s1[n * K1 + k] : s2[n * K2 + (k - K1)];
  unsigned short h = f2bf(a);
  hi[idx] = h;
  lo[idx] = f2bf(a - __uint_as_float((unsigned)h << 16));
}

// ---------------- split-bf16 MFMA GEMM: out[M][N] = [A1|A2] @ W^T ----------------
// W pre-split as [N][KT] K-major bf16 hi/lo. A staged f32->hi/lo bf16 in LDS.
// Error ~2^-17 relative: f32-equivalent for this problem's error budget.
template <int N_TOT, int K1, int K2, int WAVES_M, int WAVES_N>
__global__ __launch_bounds__(256) void k_mgemm(const float* __restrict__ A1,
                                               const float* __restrict__ A2,
                                               const unsigned short* __restrict__ Whi,
                                               const unsigned short* __restrict__ Wlo,
                                               float* __restrict__ out) {
  constexpr int KT = K1 + K2;       // 320
  constexpr int NKT = KT / 64;      // 5 K-tiles
  constexpr int WM = 64 / WAVES_M;  // wave rows
  constexpr int WN = N_TOT / WAVES_N;
  constexpr int MF = WM / 16;
  constexpr int NF = WN / 16;
  constexpr int LDA = 72;  // 64 + 8 shorts pad: row stride 144B -> 2-way bank alias only

  __shared__ unsigned short ahi_l[64 * LDA];
  __shared__ unsigned short alo_l[64 * LDA];

  const int tid = threadIdx.x;
  const size_t row0 = (size_t)blockIdx.x * 64;
  const int w = tid >> 6, l = tid & 63;
  const int lo16 = l & 15, hi4 = l >> 4;
  const int wm = w % WAVES_M, wn = w / WAVES_M;

  float4v acc[MF][NF];
#pragma unroll
  for (int m = 0; m < MF; ++m)
#pragma unroll
    for (int n = 0; n < NF; ++n) acc[m][n] = (float4v){0.f, 0.f, 0.f, 0.f};

  const int sr = tid >> 2;         // stage row 0..63
  const int sc = (tid & 3) * 16;   // stage col

  for (int kt = 0; kt < NKT; ++kt) {
    // ---- stage 64x64 f32 -> hi/lo bf16 LDS ----
    const float* src = (kt * 64 < K1)
                           ? A1 + (row0 + sr) * K1 + kt * 64 + sc
                           : A2 + (row0 + sr) * K2 + (kt * 64 - K1) + sc;
    float4 f[4];
#pragma unroll
    for (int i = 0; i < 4; ++i) f[i] = reinterpret_cast<const float4*>(src)[i];
    short8v h0, h1, l0, l1;
#pragma unroll
    for (int j = 0; j < 4; ++j) {
      float a0 = (&f[0].x)[j], a1 = (&f[1].x)[j], a2 = (&f[2].x)[j], a3 = (&f[3].x)[j];
      unsigned short ha = f2bf(a0), hb = f2bf(a1), hc = f2bf(a2), hd = f2bf(a3);
      h0[j] = (short)ha; h0[j + 4] = (short)hb; h1[j] = (short)hc; h1[j + 4] = (short)hd;
      l0[j]     = (short)f2bf(a0 - __uint_as_float((unsigned)ha << 16));
      l0[j + 4] = (short)f2bf(a1 - __uint_as_float((unsigned)hb << 16));
      l1[j]     = (short)f2bf(a2 - __uint_as_float((unsigned)hc << 16));
      l1[j + 4] = (short)f2bf(a3 - __uint_as_float((unsigned)hd << 16));
    }
    *reinterpret_cast<short8v*>(&ahi_l[sr * LDA + sc]) = h0;
    *reinterpret_cast<short8v*>(&ahi_l[sr * LDA + sc + 8]) = h1;
    *reinterpret_cast<short8v*>(&alo_l[sr * LDA + sc]) = l0;
    *reinterpret_cast<short8v*>(&alo_l[sr * LDA + sc + 8]) = l1;
    __syncthreads();

    // ---- MFMA over this K-tile (2 k-steps of 32) ----
#pragma unroll
    for (int kk = 0; kk < 2; ++kk) {
      short8v ah[MF], al[MF];
#pragma unroll
      for (int m = 0; m < MF; ++m) {
        const int ro = (wm * WM + m * 16 + lo16) * LDA + kk * 32 + hi4 * 8;
        ah[m] = *reinterpret_cast<const short8v*>(&ahi_l[ro]);
        al[m] = *reinterpret_cast<const short8v*>(&alo_l[ro]);
      }
#pragma unroll
      for (int n = 0; n < NF; ++n) {
        const size_t wo = (size_t)(wn * WN + n * 16 + lo16) * KT + kt * 64 + kk * 32 + hi4 * 8;
        short8v wh = *reinterpret_cast<const short8v*>(Whi + wo);
        short8v wl = *reinterpret_cast<const short8v*>(Wlo + wo);
#pragma unroll
        for (int m = 0; m < MF; ++m) {
          acc[m][n] = __builtin_amdgcn_mfma_f32_16x16x32_bf16(ah[m], wh, acc[m][n], 0, 0, 0);
          acc[m][n] = __builtin_amdgcn_mfma_f32_16x16x32_bf16(ah[m], wl, acc[m][n], 0, 0, 0);
          acc[m][n] = __builtin_amdgcn_mfma_f32_16x16x32_bf16(al[m], wh, acc[m][n], 0, 0, 0);
        }
      }
    }
    __syncthreads();
  }

  // ---- epilogue: C/D layout col=lane&15, row=(lane>>4)*4+reg ----
#pragma unroll
  for (int m = 0; m < MF; ++m)
#pragma unroll
    for (int n = 0; n < NF; ++n) {
      const size_t r_base = row0 + wm * WM + m * 16 + hi4 * 4;
      const int col = wn * WN + n * 16 + lo16;
#pragma unroll
      for (int rr = 0; rr < 4; ++rr)
        out[(r_base + rr) * N_TOT + col] = acc[m][n][rr];
    }
}

// ---------------- local chunk scan (zero init), writes y in place + Lstate ----------------
__global__ __launch_bounds__(512, 2) void k_scan(const float* __restrict__ Ftr,
                                                 float* __restrict__ U,
                                                 float* __restrict__ Lst,
                                                 int tasks_per_block) {
  extern __shared__ float lds[];
  float* u_lds = lds;
  float* s_lds = lds + 64 * 256;
  float* p_lds = lds + 64 * 256 + 256;

  const int tid = threadIdx.x;
  const int g = tid >> 6;
  const int d4 = tid & 63;

  float w[4][32];
#pragma unroll
  for (int j = 0; j < 32; ++j) {
#pragma unroll
    for (int o = 0; o < 4; ++o) w[o][j] = Ftr[(g * 32 + j) * 256 + o * 64 + d4];
  }

  for (int it = 0; it < tasks_per_block; ++it) {
    const int task = blockIdx.x * tasks_per_block + it;
    const int b = task >> 5;
    const int c = task & (NCHUNK - 1);
    float* ubase = U + ((size_t)b * TT + c * CHUNK) * 256;

    const float4* us = reinterpret_cast<const float4*>(ubase);
    float4* u4 = reinterpret_cast<float4*>(u_lds);
#pragma unroll
    for (int i = 0; i < 8; ++i) u4[tid + i * 512] = us[tid + i * 512];
    if (tid < 256) s_lds[tid] = 0.f;
    __syncthreads();

    for (int k = 0; k < CHUNK; ++k) {
      float a0 = 0.f, a1 = 0.f, a2 = 0.f, a3 = 0.f;
#pragma unroll
      for (int j = 0; j < 32; j += 4) {
        float4 sv = *reinterpret_cast<const float4*>(&s_lds[g * 32 + j]);
        a0 += w[0][j] * sv.x + w[0][j + 1] * sv.y + w[0][j + 2] * sv.z + w[0][j + 3] * sv.w;
        a1 += w[1][j] * sv.x + w[1][j + 1] * sv.y + w[1][j + 2] * sv.z + w[1][j + 3] * sv.w;
        a2 += w[2][j] * sv.x + w[2][j + 1] * sv.y + w[2][j + 2] * sv.z + w[2][j + 3] * sv.w;
        a3 += w[3][j] * sv.x + w[3][j + 1] * sv.y + w[3][j + 2] * sv.z + w[3][j + 3] * sv.w;
      }
      p_lds[g * 256 + d4      ] = a0;
      p_lds[g * 256 + d4 + 64 ] = a1;
      p_lds[g * 256 + d4 + 128] = a2;
      p_lds[g * 256 + d4 + 192] = a3;
      __syncthreads();
      if (tid < 256) {
        float x = u_lds[k * 256 + tid];
#pragma unroll
        for (int gg = 0; gg < 8; ++gg) x += p_lds[gg * 256 + tid];
        ubase[k * 256 + tid] = x;
        if (k == CHUNK - 1) Lst[((size_t)c * BATCH + b) * 256 + tid] = x;
        s_lds[tid] = x;
      }
      __syncthreads();
    }
  }
}

// ---------------- chunk carry: e_{c+1} = F^64 e_c + Lst[c]; writes Ebf (bf16) ----------------
__global__ __launch_bounds__(512) void k_carry(const float* __restrict__ FLtr,
                                               const float* __restrict__ state0,
                                               const float* __restrict__ Lst,
                                               unsigned short* __restrict__ Ebf) {
  __shared__ float s_lds[256];
  __shared__ float p_lds[8 * 256];
  const int tid = threadIdx.x;
  const int g = tid >> 6;
  const int d4 = tid & 63;
  const int b = blockIdx.x;

  float w[4][32];
#pragma unroll
  for (int j = 0; j < 32; ++j) {
#pragma unroll
    for (int o = 0; o < 4; ++o) w[o][j] = FLtr[(g * 32 + j) * 256 + o * 64 + d4];
  }

  if (tid < 256) {
    float e0 = state0[b * 256 + tid];
    s_lds[tid] = e0;
    Ebf[(size_t)b * 256 + tid] = f2bf(e0);
  }
  __syncthreads();

  for (int c = 0; c < NCHUNK - 1; ++c) {
    float a0 = 0.f, a1 = 0.f, a2 = 0.f, a3 = 0.f;
#pragma unroll
    for (int j = 0; j < 32; j += 4) {
      float4 sv = *reinterpret_cast<const float4*>(&s_lds[g * 32 + j]);
      a0 += w[0][j] * sv.x + w[0][j + 1] * sv.y + w[0][j + 2] * sv.z + w[0][j + 3] * sv.w;
      a1 += w[1][j] * sv.x + w[1][j + 1] * sv.y + w[1][j + 2] * sv.z + w[1][j + 3] * sv.w;
      a2 += w[2][j] * sv.x + w[2][j + 1] * sv.y + w[2][j + 2] * sv.z + w[2][j + 3] * sv.w;
      a3 += w[3][j] * sv.x + w[3][j + 1] * sv.y + w[3][j + 2] * sv.z + w[3][j + 3] * sv.w;
    }
    p_lds[g * 256 + d4      ] = a0;
    p_lds[g * 256 + d4 + 64 ] = a1;
    p_lds[g * 256 + d4 + 128] = a2;
    p_lds[g * 256 + d4 + 192] = a3;
    __syncthreads();
    if (tid < 256) {
      float x = Lst[((size_t)c * BATCH + b) * 256 + tid];
#pragma unroll
      for (int gg = 0; gg < 8; ++gg) x += p_lds[gg * 256 + tid];
      Ebf[((size_t)(c + 1) * BATCH + b) * 256 + tid] = f2bf(x);
      s_lds[tid] = x;
    }
    __syncthreads();
  }
}

// ---------------- correction: states[task, j, :] += F^{j+1} @ e[task]  (bf16 MFMA) ----------------
__global__ __launch_bounds__(256) void k_corr(const unsigned short* __restrict__ Ebf,
                                              const unsigned short* __restrict__ stackbf,
                                              float* __restrict__ states) {
  const int tb = blockIdx.x & 63;
  const int jb = blockIdx.x >> 6;
  const int tid = threadIdx.x;
  const int w = tid >> 6;
  const int l = tid & 63;
  const int lo = l & 15, hi = l >> 4;

  const int M0 = tb * 32 + (w & 1) * 16;
  const int nbase = (w >> 1) * 128;
  const unsigned short* Bj = stackbf + (size_t)jb * 65536;

  float4v acc[8];
#pragma unroll
  for (int nf = 0; nf < 8; ++nf) acc[nf] = (float4v){0.f, 0.f, 0.f, 0.f};

#pragma unroll
  for (int kk = 0; kk < 8; ++kk) {
    const int k0 = kk * 32;
    short8v a = *reinterpret_cast<const short8v*>(Ebf + (size_t)(M0 + lo) * 256 + k0 + hi * 8);
#pragma unroll
    for (int nf = 0; nf < 8; ++nf) {
      const int d0 = nbase + nf * 16;
      short8v bv = *reinterpret_cast<const short8v*>(Bj + (size_t)(d0 + lo) * 256 + k0 + hi * 8);
      acc[nf] = __builtin_amdgcn_mfma_f32_16x16x32_bf16(a, bv, acc[nf], 0, 0, 0);
    }
  }

#pragma unroll
  for (int nf = 0; nf < 8; ++nf) {
    const int d = nbase + nf * 16 + lo;
#pragma unroll
    for (int r = 0; r < 4; ++r) {
      const int task = M0 + hi * 4 + r;
      const int bb = task & 63, cc = task >> 6;
      size_t addr = (((size_t)bb * TT) + cc * CHUNK + jb) * 256 + d;
      states[addr] = states[addr] + acc[nf][r];
    }
  }
}

extern "C" void kernel_launch(void* const* d_in, const int* in_sizes, int n_in,
                              void* d_out, int out_size, void* d_ws, size_t ws_size,
                              hipStream_t stream) {
  const float* state  = (const float*)d_in[0];
  const float* inputs = (const float*)d_in[1];
  const float* eps_W  = (const float*)d_in[2];
  const float* eps_V  = (const float*)d_in[3];
  const float* F      = (const float*)d_in[4];
  const float* B_mat  = (const float*)d_in[5];
  const float* H      = (const float*)d_in[6];
  const float* SW     = (const float*)d_in[7];
  const float* SV     = (const float*)d_in[8];

  float* out = (float*)d_out;
  float* states_out = out;                                 // [64][2048][256]
  float* obs_out = out + (size_t)BATCH * TT * S_DIM;       // [64][2048][64]

  // ws: Ftr, FLtr f32; W splits bf16 (~924 KB total)
  float* ws   = (float*)d_ws;
  float* Ftr  = ws;                       // [256][256]
  float* FLtr = Ftr + 65536;              // [256][256]
  unsigned short* whi1 = (unsigned short*)(FLtr + 65536);  // [256][320]
  unsigned short* wlo1 = whi1 + 81920;
  unsigned short* whi2 = wlo1 + 81920;                     // [64][320]
  unsigned short* wlo2 = whi2 + 20480;

  // big scratch in the dead obs region
  float* Lst              = obs_out;                                  // [32][64][256]
  float* stack_F          = Lst + (size_t)NCHUNK * BATCH * 256;       // [64][256][256]
  unsigned short* stackbf = (unsigned short*)(stack_F + (size_t)64 * 65536);
  unsigned short* Ebf     = stackbf + (size_t)64 * 65536;             // [32][64][256]

  k_transpose<<<256, 256, 0, stream>>>(F, Ftr, 256, 256);

  // power stack F^1..F^64 by doubling
  hipMemcpyAsync(stack_F, F, 65536 * sizeof(float), hipMemcpyDeviceToDevice, stream);
  k_powstage<<<1 * 256, 256, 0, stream>>>(stack_F, 1);
  k_powstage<<<2 * 256, 256, 0, stream>>>(stack_F, 2);
  k_powstage<<<4 * 256, 256, 0, stream>>>(stack_F, 4);
  k_powstage<<<8 * 256, 256, 0, stream>>>(stack_F, 8);
  k_powstage<<<16 * 256, 256, 0, stream>>>(stack_F, 16);
  k_powstage<<<32 * 256, 256, 0, stream>>>(stack_F, 32);
  k_transpose<<<256, 256, 0, stream>>>(stack_F + (size_t)63 * 65536, FLtr, 256, 256);
  k_bfcvt<<<64 * 65536 / 4 / 256, 256, 0, stream>>>(stack_F, stackbf);

  // weight splits: [N][K] K-major hi/lo (no transpose needed — rows are native)
  k_wsplit<<<320, 256, 0, stream>>>(B_mat, SW, 64, 256, whi1, wlo1, 256 * 320);
  k_wsplit<<<80, 256, 0, stream>>>(H, SV, 256, 64, whi2, wlo2, 64 * 320);

  // U = inputs@B^T + eps_W@SW^T  (split-bf16 MFMA, f32-equivalent precision)
  k_mgemm<256, 64, 256, 2, 2><<<BATCH * TT / 64, 256, 0, stream>>>(
      inputs, eps_W, whi1, wlo1, states_out);

  // pass 1: local scans (zero init), y in place + Lstate
  const size_t lds_bytes = (CHUNK * 256 + 256 + 8 * 256) * sizeof(float);
  k_scan<<<512, 512, lds_bytes, stream>>>(Ftr, states_out, Lst, NTASK / 512);

  // carry across chunks -> Ebf
  k_carry<<<BATCH, 512, 0, stream>>>(FLtr, state, Lst, Ebf);

  // correction: states = y + F^{j+1} e
  k_corr<<<64 * 64, 256, 0, stream>>>(Ebf, stackbf, states_out);

  // observations = states@H^T + eps_V@SV^T (split-bf16 MFMA)
  k_mgemm<64, 256, 64, 4, 1><<<BATCH * TT / 64, 256, 0, stream>>>(
      states_out, eps_V, whi2, wlo2, obs_out);
}

// Round 5
// 708.667 us; speedup vs baseline: 2.0208x; 1.3971x over previous
//
#include <hip/hip_runtime.h>

#define S_DIM 256
#define I_DIM 64
#define O_DIM 64
#define BATCH 64
#define TT 2048
#define CHUNK 32
#define NCHUNK (TT / CHUNK)     // 64
#define NTASK (BATCH * NCHUNK)  // 4096

typedef __attribute__((ext_vector_type(8))) short short8v;      // 8 bf16
typedef _Float16 half8v __attribute__((ext_vector_type(8)));    // 8 fp16
typedef __attribute__((ext_vector_type(4))) float float4v;      // MFMA acc

__device__ inline unsigned short f2bf(float f) {
  unsigned x = __float_as_uint(f);
  unsigned r = (x + 0x7FFFu + ((x >> 16) & 1u)) >> 16;  // RNE
  return (unsigned short)r;
}

// ------------- power-stack doubling: stack[m+j] = stack[j] @ stack[m-1] -------------
// stack[p] = F^(p+1), row-major. Launch <<<m*256, 256>>>.
__global__ void k_powstage(float* __restrict__ stack, int m) {
  const int j = blockIdx.x >> 8;
  const int i = blockIdx.x & 255;
  const int d = threadIdx.x;
  const float* A = stack + (size_t)j * 65536 + i * 256;
  const float* Bm = stack + (size_t)(m - 1) * 65536;
  float acc = 0.f;
#pragma unroll 8
  for (int k = 0; k < 256; ++k) acc += A[k] * Bm[k * 256 + d];
  stack[(size_t)(m + j) * 65536 + i * 256 + d] = acc;
}

// ------------- f32 -> bf16 elementwise (float4 granularity) -------------
__global__ void k_bfcvt(const float* __restrict__ src, unsigned short* __restrict__ dst) {
  int i = blockIdx.x * 256 + threadIdx.x;
  float4 v = reinterpret_cast<const float4*>(src)[i];
  ushort4 o;
  o.x = f2bf(v.x); o.y = f2bf(v.y); o.z = f2bf(v.z); o.w = f2bf(v.w);
  reinterpret_cast<ushort4*>(dst)[i] = o;
}

// ------------- f32 matrix -> fp16 hi/lo split (exact 2-term: residual ~2^-24) -------------
__global__ void k_fsplit16(const float* __restrict__ src, _Float16* __restrict__ hi,
                           _Float16* __restrict__ lo) {
  int idx = blockIdx.x * 256 + threadIdx.x;
  float a = src[idx];
  _Float16 h = (_Float16)a;
  hi[idx] = h;
  lo[idx] = (_Float16)(a - (float)h);
}

// ------------- weight split: Wd[n][k] = concat(s1,s2) rows; hi/lo bf16 -------------
__global__ void k_wsplit(const float* __restrict__ s1, const float* __restrict__ s2,
                         int K1, int K2, unsigned short* __restrict__ hi,
                         unsigned short* __restrict__ lo, int total) {
  int idx = blockIdx.x * 256 + threadIdx.x;
  if (idx >= total) return;
  int KT = K1 + K2;
  int n = idx / KT, k = idx - n * KT;
  float a = (k < K1) ? s1[n * K1 + k] : s2[n * K2 + (k - K1)];
  unsigned short h = f2bf(a);
  hi[idx] = h;
  lo[idx] = f2bf(a - __uint_as_float((unsigned)h << 16));
}

// ---------------- split-bf16 MFMA GEMM: out[M][N] = [A1|A2] @ W^T ----------------
template <int N_TOT, int K1, int K2, int WAVES_M, int WAVES_N>
__global__ __launch_bounds__(256) void k_mgemm(const float* __restrict__ A1,
                                               const float* __restrict__ A2,
                                               const unsigned short* __restrict__ Whi,
                                               const unsigned short* __restrict__ Wlo,
                                               float* __restrict__ out) {
  constexpr int KT = K1 + K2;
  constexpr int NKT = KT / 64;
  constexpr int WM = 64 / WAVES_M;
  constexpr int WN = N_TOT / WAVES_N;
  constexpr int MF = WM / 16;
  constexpr int NF = WN / 16;
  constexpr int LDA = 72;

  __shared__ unsigned short ahi_l[64 * LDA];
  __shared__ unsigned short alo_l[64 * LDA];

  const int tid = threadIdx.x;
  const size_t row0 = (size_t)blockIdx.x * 64;
  const int w = tid >> 6, l = tid & 63;
  const int lo16 = l & 15, hi4 = l >> 4;
  const int wm = w % WAVES_M, wn = w / WAVES_M;

  float4v acc[MF][NF];
#pragma unroll
  for (int m = 0; m < MF; ++m)
#pragma unroll
    for (int n = 0; n < NF; ++n) acc[m][n] = (float4v){0.f, 0.f, 0.f, 0.f};

  const int sr = tid >> 2;
  const int sc = (tid & 3) * 16;

  for (int kt = 0; kt < NKT; ++kt) {
    const float* src = (kt * 64 < K1)
                           ? A1 + (row0 + sr) * K1 + kt * 64 + sc
                           : A2 + (row0 + sr) * K2 + (kt * 64 - K1) + sc;
    float4 f[4];
#pragma unroll
    for (int i = 0; i < 4; ++i) f[i] = reinterpret_cast<const float4*>(src)[i];
    short8v h0, h1, l0, l1;
#pragma unroll
    for (int j = 0; j < 4; ++j) {
      float a0 = (&f[0].x)[j], a1 = (&f[1].x)[j], a2 = (&f[2].x)[j], a3 = (&f[3].x)[j];
      unsigned short ha = f2bf(a0), hb = f2bf(a1), hc = f2bf(a2), hd = f2bf(a3);
      h0[j] = (short)ha; h0[j + 4] = (short)hb; h1[j] = (short)hc; h1[j + 4] = (short)hd;
      l0[j]     = (short)f2bf(a0 - __uint_as_float((unsigned)ha << 16));
      l0[j + 4] = (short)f2bf(a1 - __uint_as_float((unsigned)hb << 16));
      l1[j]     = (short)f2bf(a2 - __uint_as_float((unsigned)hc << 16));
      l1[j + 4] = (short)f2bf(a3 - __uint_as_float((unsigned)hd << 16));
    }
    *reinterpret_cast<short8v*>(&ahi_l[sr * LDA + sc]) = h0;
    *reinterpret_cast<short8v*>(&ahi_l[sr * LDA + sc + 8]) = h1;
    *reinterpret_cast<short8v*>(&alo_l[sr * LDA + sc]) = l0;
    *reinterpret_cast<short8v*>(&alo_l[sr * LDA + sc + 8]) = l1;
    __syncthreads();

#pragma unroll
    for (int kk = 0; kk < 2; ++kk) {
      short8v ah[MF], al[MF];
#pragma unroll
      for (int m = 0; m < MF; ++m) {
        const int ro = (wm * WM + m * 16 + lo16) * LDA + kk * 32 + hi4 * 8;
        ah[m] = *reinterpret_cast<const short8v*>(&ahi_l[ro]);
        al[m] = *reinterpret_cast<const short8v*>(&alo_l[ro]);
      }
#pragma unroll
      for (int n = 0; n < NF; ++n) {
        const size_t wo = (size_t)(wn * WN + n * 16 + lo16) * KT + kt * 64 + kk * 32 + hi4 * 8;
        short8v wh = *reinterpret_cast<const short8v*>(Whi + wo);
        short8v wl = *reinterpret_cast<const short8v*>(Wlo + wo);
#pragma unroll
        for (int m = 0; m < MF; ++m) {
          acc[m][n] = __builtin_amdgcn_mfma_f32_16x16x32_bf16(ah[m], wh, acc[m][n], 0, 0, 0);
          acc[m][n] = __builtin_amdgcn_mfma_f32_16x16x32_bf16(ah[m], wl, acc[m][n], 0, 0, 0);
          acc[m][n] = __builtin_amdgcn_mfma_f32_16x16x32_bf16(al[m], wh, acc[m][n], 0, 0, 0);
        }
      }
    }
    __syncthreads();
  }

#pragma unroll
  for (int m = 0; m < MF; ++m)
#pragma unroll
    for (int n = 0; n < NF; ++n) {
      const size_t r_base = row0 + wm * WM + m * 16 + hi4 * 4;
      const int col = wn * WN + n * 16 + lo16;
#pragma unroll
      for (int rr = 0; rr < 4; ++rr)
        out[(r_base + rr) * N_TOT + col] = acc[m][n][rr];
    }
}

// ---------------- MFMA chunk scan: 16 tasks/block, 32 steps, fp16-2split F ----------------
// s' = F s + u. y (zero-init local states) written over U in place; last state -> Lst.
// 16 waves: wave wv owns output dims [wv*16, wv*16+16). F-slice resident in VGPRs.
__global__ __launch_bounds__(1024, 4) void k_mscan(const _Float16* __restrict__ Fhi,
                                                   const _Float16* __restrict__ Flo,
                                                   float* __restrict__ U,
                                                   float* __restrict__ Lst) {
  __shared__ _Float16 sh[16 * 264];
  __shared__ _Float16 sl[16 * 264];

  const int tid = threadIdx.x;
  const int wv = tid >> 6;
  const int l = tid & 63;
  const int lo16 = l & 15, hi4 = l >> 4;
  const int dcol = wv * 16 + lo16;

  const int c = blockIdx.x >> 2;          // chunk
  const int b0 = (blockIdx.x & 3) * 16;   // batch base (16 tasks, same chunk)

  // resident F fragments: rows = output dims dcol, k-contiguous
  half8v fh[8], fl[8];
#pragma unroll
  for (int kk = 0; kk < 8; ++kk) {
    const size_t fo = (size_t)dcol * 256 + kk * 32 + hi4 * 8;
    fh[kk] = *reinterpret_cast<const half8v*>(Fhi + fo);
    fl[kk] = *reinterpret_cast<const half8v*>(Flo + fo);
  }

  const size_t ustr = (size_t)TT * 256;
  float* ub = U + ((size_t)b0 * TT + c * CHUNK) * 256 + dcol;

  float u_cur[4], u_nxt[4];
#pragma unroll
  for (int r = 0; r < 4; ++r) u_cur[r] = ub[(size_t)(hi4 * 4 + r) * ustr];

  for (int k = 0; k < CHUNK; ++k) {
    if (k < CHUNK - 1) {
#pragma unroll
      for (int r = 0; r < 4; ++r)
        u_nxt[r] = ub[(size_t)(hi4 * 4 + r) * ustr + (k + 1) * 256];
    }
    float4v acc;
#pragma unroll
    for (int r = 0; r < 4; ++r) acc[r] = u_cur[r];

    if (k) {
#pragma unroll
      for (int kk = 0; kk < 8; ++kk) {
        const int ao = lo16 * 264 + kk * 32 + hi4 * 8;
        half8v ah = *reinterpret_cast<const half8v*>(&sh[ao]);
        half8v al = *reinterpret_cast<const half8v*>(&sl[ao]);
        acc = __builtin_amdgcn_mfma_f32_16x16x32_f16(ah, fh[kk], acc, 0, 0, 0);
        acc = __builtin_amdgcn_mfma_f32_16x16x32_f16(ah, fl[kk], acc, 0, 0, 0);
        acc = __builtin_amdgcn_mfma_f32_16x16x32_f16(al, fh[kk], acc, 0, 0, 0);
      }
    }

    // write y, split state to fp16 hi/lo
    _Float16 xh[4], xl[4];
#pragma unroll
    for (int r = 0; r < 4; ++r) {
      float x = acc[r];
      ub[(size_t)(hi4 * 4 + r) * ustr + k * 256] = x;
      if (k == CHUNK - 1) Lst[((size_t)c * BATCH + b0 + hi4 * 4 + r) * 256 + dcol] = x;
      _Float16 h = (_Float16)x;
      xh[r] = h;
      xl[r] = (_Float16)(x - (float)h);
    }
    __syncthreads();  // all waves done reading s_lds for step k
#pragma unroll
    for (int r = 0; r < 4; ++r) {
      const int m = hi4 * 4 + r;
      sh[m * 264 + dcol] = xh[r];
      sl[m * 264 + dcol] = xl[r];
    }
    __syncthreads();  // writes visible for step k+1
#pragma unroll
    for (int r = 0; r < 4; ++r) u_cur[r] = u_nxt[r];
  }
}

// ---------------- MFMA chunk carry: e_{c+1} = F^32 e_c + Lst[c] -> Ebf (bf16) ----------------
// 4 blocks x 16 batches, 63 sequential steps. Same skeleton as k_mscan.
__global__ __launch_bounds__(1024, 4) void k_mcarry(const _Float16* __restrict__ FLhi,
                                                    const _Float16* __restrict__ FLlo,
                                                    const float* __restrict__ state0,
                                                    const float* __restrict__ Lst,
                                                    unsigned short* __restrict__ Ebf) {
  __shared__ _Float16 sh[16 * 264];
  __shared__ _Float16 sl[16 * 264];

  const int tid = threadIdx.x;
  const int wv = tid >> 6;
  const int l = tid & 63;
  const int lo16 = l & 15, hi4 = l >> 4;
  const int dcol = wv * 16 + lo16;
  const int b0 = blockIdx.x * 16;

  half8v fh[8], fl[8];
#pragma unroll
  for (int kk = 0; kk < 8; ++kk) {
    const size_t fo = (size_t)dcol * 256 + kk * 32 + hi4 * 8;
    fh[kk] = *reinterpret_cast<const half8v*>(FLhi + fo);
    fl[kk] = *reinterpret_cast<const half8v*>(FLlo + fo);
  }

  // init: e_0 = state0; Ebf[0]
#pragma unroll
  for (int r = 0; r < 4; ++r) {
    const int m = hi4 * 4 + r;
    float x = state0[(size_t)(b0 + m) * 256 + dcol];
    Ebf[(size_t)(b0 + m) * 256 + dcol] = f2bf(x);
    _Float16 h = (_Float16)x;
    sh[m * 264 + dcol] = h;
    sl[m * 264 + dcol] = (_Float16)(x - (float)h);
  }
  __syncthreads();

  for (int cstep = 0; cstep < NCHUNK - 1; ++cstep) {
    float4v acc;
#pragma unroll
    for (int r = 0; r < 4; ++r)
      acc[r] = Lst[((size_t)cstep * BATCH + b0 + hi4 * 4 + r) * 256 + dcol];
#pragma unroll
    for (int kk = 0; kk < 8; ++kk) {
      const int ao = lo16 * 264 + kk * 32 + hi4 * 8;
      half8v ah = *reinterpret_cast<const half8v*>(&sh[ao]);
      half8v al = *reinterpret_cast<const half8v*>(&sl[ao]);
      acc = __builtin_amdgcn_mfma_f32_16x16x32_f16(ah, fh[kk], acc, 0, 0, 0);
      acc = __builtin_amdgcn_mfma_f32_16x16x32_f16(ah, fl[kk], acc, 0, 0, 0);
      acc = __builtin_amdgcn_mfma_f32_16x16x32_f16(al, fh[kk], acc, 0, 0, 0);
    }
    _Float16 xh[4], xl[4];
#pragma unroll
    for (int r = 0; r < 4; ++r) {
      float x = acc[r];
      Ebf[((size_t)(cstep + 1) * BATCH + b0 + hi4 * 4 + r) * 256 + dcol] = f2bf(x);
      _Float16 h = (_Float16)x;
      xh[r] = h;
      xl[r] = (_Float16)(x - (float)h);
    }
    __syncthreads();
#pragma unroll
    for (int r = 0; r < 4; ++r) {
      const int m = hi4 * 4 + r;
      sh[m * 264 + dcol] = xh[r];
      sl[m * 264 + dcol] = xl[r];
    }
    __syncthreads();
  }
}

// ---------------- correction: states[task, j, :] += F^{j+1} @ e[task]  (bf16 MFMA) ----------------
__global__ __launch_bounds__(256) void k_corr(const unsigned short* __restrict__ Ebf,
                                              const unsigned short* __restrict__ stackbf,
                                              float* __restrict__ states) {
  const int tb = blockIdx.x & 127;  // 128 task-blocks of 32 (NTASK=4096)
  const int jb = blockIdx.x >> 7;   // j in [0,32)
  const int tid = threadIdx.x;
  const int w = tid >> 6;
  const int l = tid & 63;
  const int lo = l & 15, hi = l >> 4;

  const int M0 = tb * 32 + (w & 1) * 16;
  const int nbase = (w >> 1) * 128;
  const unsigned short* Bj = stackbf + (size_t)jb * 65536;

  float4v acc[8];
#pragma unroll
  for (int nf = 0; nf < 8; ++nf) acc[nf] = (float4v){0.f, 0.f, 0.f, 0.f};

#pragma unroll
  for (int kk = 0; kk < 8; ++kk) {
    const int k0 = kk * 32;
    short8v a = *reinterpret_cast<const short8v*>(Ebf + (size_t)(M0 + lo) * 256 + k0 + hi * 8);
#pragma unroll
    for (int nf = 0; nf < 8; ++nf) {
      const int d0 = nbase + nf * 16;
      short8v bv = *reinterpret_cast<const short8v*>(Bj + (size_t)(d0 + lo) * 256 + k0 + hi * 8);
      acc[nf] = __builtin_amdgcn_mfma_f32_16x16x32_bf16(a, bv, acc[nf], 0, 0, 0);
    }
  }

#pragma unroll
  for (int nf = 0; nf < 8; ++nf) {
    const int d = nbase + nf * 16 + lo;
#pragma unroll
    for (int r = 0; r < 4; ++r) {
      const int task = M0 + hi * 4 + r;           // task = c*64 + b
      const int bb = task & 63, cc = task >> 6;
      size_t addr = (((size_t)bb * TT) + cc * CHUNK + jb) * 256 + d;
      states[addr] = states[addr] + acc[nf][r];
    }
  }
}

extern "C" void kernel_launch(void* const* d_in, const int* in_sizes, int n_in,
                              void* d_out, int out_size, void* d_ws, size_t ws_size,
                              hipStream_t stream) {
  const float* state  = (const float*)d_in[0];
  const float* inputs = (const float*)d_in[1];
  const float* eps_W  = (const float*)d_in[2];
  const float* eps_V  = (const float*)d_in[3];
  const float* F      = (const float*)d_in[4];
  const float* B_mat  = (const float*)d_in[5];
  const float* H      = (const float*)d_in[6];
  const float* SW     = (const float*)d_in[7];
  const float* SV     = (const float*)d_in[8];

  float* out = (float*)d_out;
  float* states_out = out;                                 // [64][2048][256]
  float* obs_out = out + (size_t)BATCH * TT * S_DIM;       // [64][2048][64]

  // ws (~912 KB): bf16 weight splits + fp16 F splits
  unsigned short* ws16 = (unsigned short*)d_ws;
  unsigned short* whi1 = ws16;                 // [256][320]
  unsigned short* wlo1 = whi1 + 81920;
  unsigned short* whi2 = wlo1 + 81920;         // [64][320]
  unsigned short* wlo2 = whi2 + 20480;
  _Float16* Fhi  = (_Float16*)(wlo2 + 20480);  // [256][256]
  _Float16* Flo  = Fhi + 65536;
  _Float16* FLhi = Flo + 65536;                // (F^32) [256][256]
  _Float16* FLlo = FLhi + 65536;

  // big scratch in the dead obs region (18 MB of 33.5 MB)
  float* Lst              = obs_out;                                   // [64][64][256] f32
  float* stack_F          = Lst + (size_t)NCHUNK * BATCH * 256;        // [32][256][256] f32
  unsigned short* stackbf = (unsigned short*)(stack_F + (size_t)32 * 65536);
  unsigned short* Ebf     = stackbf + (size_t)32 * 65536;              // [64][64][256] bf16

  // power stack F^1..F^32 by doubling
  hipMemcpyAsync(stack_F, F, 65536 * sizeof(float), hipMemcpyDeviceToDevice, stream);
  k_powstage<<<1 * 256, 256, 0, stream>>>(stack_F, 1);
  k_powstage<<<2 * 256, 256, 0, stream>>>(stack_F, 2);
  k_powstage<<<4 * 256, 256, 0, stream>>>(stack_F, 4);
  k_powstage<<<8 * 256, 256, 0, stream>>>(stack_F, 8);
  k_powstage<<<16 * 256, 256, 0, stream>>>(stack_F, 16);
  k_bfcvt<<<32 * 65536 / 4 / 256, 256, 0, stream>>>(stack_F, stackbf);

  // fp16 splits for the scan/carry matrices
  k_fsplit16<<<256, 256, 0, stream>>>(F, Fhi, Flo);
  k_fsplit16<<<256, 256, 0, stream>>>(stack_F + (size_t)31 * 65536, FLhi, FLlo);

  // bf16 weight splits (K-major concat rows)
  k_wsplit<<<320, 256, 0, stream>>>(B_mat, SW, 64, 256, whi1, wlo1, 256 * 320);
  k_wsplit<<<80, 256, 0, stream>>>(H, SV, 256, 64, whi2, wlo2, 64 * 320);

  // U = inputs@B^T + eps_W@SW^T
  k_mgemm<256, 64, 256, 2, 2><<<BATCH * TT / 64, 256, 0, stream>>>(
      inputs, eps_W, whi1, wlo1, states_out);

  // pass 1: MFMA local scans (zero init), y in place + Lst
  k_mscan<<<NTASK / 16, 1024, 0, stream>>>(Fhi, Flo, states_out, Lst);

  // carry across chunks -> Ebf
  k_mcarry<<<BATCH / 16, 1024, 0, stream>>>(FLhi, FLlo, state, Lst, Ebf);

  // correction: states = y + F^{j+1} e
  k_corr<<<32 * 128, 256, 0, stream>>>(Ebf, stackbf, states_out);

  // observations = states@H^T + eps_V@SV^T
  k_mgemm<64, 256, 64, 4, 1><<<BATCH * TT / 64, 256, 0, stream>>>(
      states_out, eps_V, whi2, wlo2, obs_out);
}